// Round 15
// baseline (387.487 us; speedup 1.0000x reference)
//
#include <hip/hip_runtime.h>
#include <math.h>

// Problem constants
#define NN 2048
#define MM 16
#define DD 512
#define DE 128
#define HH 8
#define GG 50
#define DH 64
#define DEH 16

typedef __attribute__((ext_vector_type(8))) short bf8_t;   // 8 bf16 = 4 VGPRs
typedef __attribute__((ext_vector_type(4))) float f4_t;    // MFMA accumulator
typedef __attribute__((ext_vector_type(2))) float f2_t;    // packed f32 pair
typedef unsigned short us;

// Async global->LDS 16B copy. LDS dest must be wave-uniform base; HW writes
// base + lane*16. Global src is per-lane.
__device__ __forceinline__ void gload16(const us* g, us* l) {
    __builtin_amdgcn_global_load_lds(
        (const __attribute__((address_space(1))) unsigned int*)g,
        (__attribute__((address_space(3))) unsigned int*)l, 16, 0, 0);
}

// Branchless tanh-approx GELU (max |err| vs erf-gelu ~3e-3)
__device__ __forceinline__ float gelu_f(float x) {
    float u = 1.5957691216f * fmaf(0.044715f * x, x * x, x);
    u = fminf(fmaxf(u, -30.f), 30.f);
    float e = __expf(u);
    float t = fmaf(-2.f, __builtin_amdgcn_rcpf(e + 1.f), 1.f);  // tanh(u/2)
    float hx = 0.5f * x;
    return fmaf(hx, t, hx);
}

// Packed-pair gelu, clamp-free (exp overflow saturates to the right limits).
__device__ __forceinline__ f2_t gelu2(f2_t x) {
    f2_t u = ((x * 0.044715f) * (x * x) + x) * 1.5957691216f;
    f2_t e1;
    e1.x = __expf(u.x) + 1.f;
    e1.y = __expf(u.y) + 1.f;
    f2_t r;
    r.x = __builtin_amdgcn_rcpf(e1.x);
    r.y = __builtin_amdgcn_rcpf(e1.y);
    f2_t t = r * (-2.f) + 1.f;
    f2_t hx = x * 0.5f;
    return hx * t + hx;
}

__device__ __forceinline__ float wsum(float v) {
#pragma unroll
    for (int o = 32; o; o >>= 1) v += __shfl_xor(v, o, 64);
    return v;
}

__device__ __forceinline__ us f2bf(float x) {
    union { float f; unsigned int u; } v;
    v.f = x;
    unsigned int r = v.u + 0x7FFFu + ((v.u >> 16) & 1u);  // RNE
    return (us)(r >> 16);
}

__device__ __forceinline__ float bfu(unsigned int u) {
    union { unsigned int x; float f; } v;
    v.x = u;
    return v.f;
}
#define BF_LO(u) bfu((u) << 16)
#define BF_HI(u) bfu((u) & 0xFFFF0000u)
__device__ __forceinline__ float b2f(us u) { return bfu((unsigned int)u << 16); }

// ---------------------------------------------------------------------------
// Row-wise (optional GELU) + LayerNorm. Writes fp32 and/or bf16 output.
// ---------------------------------------------------------------------------
__global__ __launch_bounds__(256) void act_ln_kernel(float* __restrict__ outF,
                                                     us* __restrict__ outB,
                                                     const float* __restrict__ x,
                                                     int C, int do_gelu) {
    int row = blockIdx.x, tid = threadIdx.x;
    int nv = C >> 8;  // C is 512 or 2048
    float v[8];
    float s = 0.f, ss = 0.f;
    for (int i = 0; i < nv; ++i) {
        float val = x[(size_t)row * C + tid + (i << 8)];
        if (do_gelu) val = gelu_f(val);
        v[i] = val;
        s += val;
        ss += val * val;
    }
    __shared__ float red[4][2];
    s = wsum(s);
    ss = wsum(ss);
    int wid = tid >> 6, lane = tid & 63;
    if (lane == 0) { red[wid][0] = s; red[wid][1] = ss; }
    __syncthreads();
    s = red[0][0] + red[1][0] + red[2][0] + red[3][0];
    ss = red[0][1] + red[1][1] + red[2][1] + red[3][1];
    float mean = s / (float)C;
    float var = ss / (float)C - mean * mean;
    float rs = rsqrtf(var + 1e-5f);
    for (int i = 0; i < nv; ++i) {
        float y = (v[i] - mean) * rs;
        size_t idx = (size_t)row * C + tid + (i << 8);
        if (outF) outF[idx] = y;
        if (outB) outB[idx] = f2bf(y);
    }
}

// ---------------------------------------------------------------------------
// Split-K=2 combine + bias + GELU + LN -> bf16 (row-wise, C=512).
// ---------------------------------------------------------------------------
__global__ __launch_bounds__(256) void combine2ln_kernel(const float* __restrict__ pk,
                                                         const float* __restrict__ bias,
                                                         us* __restrict__ outB) {
    int row = blockIdx.x, tid = threadIdx.x;
    size_t b = (size_t)row * 512;
    float v0 = gelu_f(pk[b + tid] + pk[1048576 + b + tid] + bias[tid]);
    float v1 = gelu_f(pk[b + 256 + tid] + pk[1048576 + b + 256 + tid] + bias[256 + tid]);
    __shared__ float red[4][2];
    float s = wsum(v0 + v1);
    float ss = wsum(fmaf(v0, v0, v1 * v1));
    int wid = tid >> 6, lane = tid & 63;
    if (lane == 0) { red[wid][0] = s; red[wid][1] = ss; }
    __syncthreads();
    s = red[0][0] + red[1][0] + red[2][0] + red[3][0];
    ss = red[0][1] + red[1][1] + red[2][1] + red[3][1];
    float mean = s * (1.f / 512.f);
    float var = ss * (1.f / 512.f) - mean * mean;
    float rs = rsqrtf(var + 1e-5f);
    outB[b + tid] = f2bf((v0 - mean) * rs);
    outB[b + 256 + tid] = f2bf((v1 - mean) * rs);
}

// ---------------------------------------------------------------------------
// Split-K=2 combine + bias + resid -> fp32 + bf16 (elementwise, 2048x512).
// ---------------------------------------------------------------------------
__global__ __launch_bounds__(256) void combine2_kernel(const float* __restrict__ pk,
                                                       const float* __restrict__ bias,
                                                       const float* __restrict__ resid,
                                                       float* __restrict__ outF,
                                                       us* __restrict__ outB) {
    int idx = blockIdx.x * 256 + threadIdx.x;
    float v = pk[idx] + pk[idx + 1048576] + bias[idx & 511] + resid[idx];
    outF[idx] = v;
    outB[idx] = f2bf(v);
}

// ---------------------------------------------------------------------------
// Split-K=4 combine for wm2: tok_out = sum4 + bias + resid, fp32 + bf16.
// ---------------------------------------------------------------------------
__global__ __launch_bounds__(256) void wm2_combine(const float* __restrict__ pk,
                                                   const float* __restrict__ bias,
                                                   const float* __restrict__ resid,
                                                   float* __restrict__ outF,
                                                   us* __restrict__ outB) {
    int idx = blockIdx.x * 256 + threadIdx.x;
    float v = pk[idx] + pk[idx + 1048576] + pk[idx + 2097152] + pk[idx + 3145728] +
              bias[idx & 511] + resid[idx];
    outF[idx] = v;
    outB[idx] = f2bf(v);
}

// ---------------------------------------------------------------------------
// Split-K=4 combine for wg2: gene_out = sum4 + bias (2048x50 fp32).
// ---------------------------------------------------------------------------
__global__ __launch_bounds__(256) void wg2_combine(const float* __restrict__ pk,
                                                   const float* __restrict__ bias,
                                                   float* __restrict__ outF) {
    int idx = blockIdx.x * 256 + threadIdx.x;
    if (idx >= 102400) return;
    float v = pk[idx] + pk[idx + 102400] + pk[idx + 204800] + pk[idx + 307200] +
              bias[idx % 50];
    outF[idx] = v;
}

// ---------------------------------------------------------------------------
// Fused LN(token_embs)->bf16 (blocks 0..2047) + frame projections (blocks
// 2048..2175; 16 nodes per block).
// ---------------------------------------------------------------------------
__global__ __launch_bounds__(256) void lnproj_kernel(const float* __restrict__ te,
                                                     us* __restrict__ x_ln_bf,
                                                     const float* __restrict__ coords,
                                                     const int* __restrict__ nbr,
                                                     float* __restrict__ projs,
                                                     float* __restrict__ rns) {
    int tid = threadIdx.x;
    if (blockIdx.x < 2048) {
        int row = blockIdx.x;
        float v0 = te[(size_t)row * 512 + tid];
        float v1 = te[(size_t)row * 512 + 256 + tid];
        __shared__ float red[4][2];
        float s = wsum(v0 + v1);
        float ss = wsum(fmaf(v0, v0, v1 * v1));
        int wid = tid >> 6, lane = tid & 63;
        if (lane == 0) { red[wid][0] = s; red[wid][1] = ss; }
        __syncthreads();
        s = red[0][0] + red[1][0] + red[2][0] + red[3][0];
        ss = red[0][1] + red[1][1] + red[2][1] + red[3][1];
        float mean = s * (1.f / 512.f);
        float var = ss * (1.f / 512.f) - mean * mean;
        float rs = rsqrtf(var + 1e-5f);
        x_ln_bf[(size_t)row * 512 + tid] = f2bf((v0 - mean) * rs);
        x_ln_bf[(size_t)row * 512 + 256 + tid] = f2bf((v1 - mean) * rs);
        return;
    }
    int node = (blockIdx.x - 2048) * 16 + (tid >> 4);
    int m = tid & 15;
    float cx = coords[node * 2], cy = coords[node * 2 + 1];
    int j = nbr[node * 16 + m];
    float rx = coords[j * 2] - cx;
    float ry = coords[j * 2 + 1] - cy;
    float rn = sqrtf(rx * rx + ry * ry);
    float mx = rx, my = ry;
#pragma unroll
    for (int o = 8; o; o >>= 1) { mx += __shfl_xor(mx, o, 16); my += __shfl_xor(my, o, 16); }
    mx *= 0.0625f;
    my *= 0.0625f;
    float xcx = rx - mx, xcy = ry - my;
    float sxx = xcx * xcx, sxy = xcx * xcy, syy = xcy * xcy;
#pragma unroll
    for (int o = 8; o; o >>= 1) {
        sxx += __shfl_xor(sxx, o, 16);
        sxy += __shfl_xor(sxy, o, 16);
        syy += __shfl_xor(syy, o, 16);
    }
    double a = (double)sxx, b = (double)sxy, c = (double)syy;
    double diff = 0.5 * (a - c);
    double disc = sqrt(diff * diff + b * b);
    double l2 = 0.5 * (a + c) + disc;
    double v2x = b, v2y = l2 - a;
    double nn2 = sqrt(v2x * v2x + v2y * v2y);
    if (nn2 < 1e-30) { v2x = (a >= c) ? 1.0 : 0.0; v2y = 1.0 - v2x; nn2 = 1.0; }
    v2x /= nn2;
    v2y /= nn2;
    double v1x = -v2y, v1y = v2x;  // eigenvector of smaller eigenvalue
    int row = node * 16 + m;
    projs[row * 2] = (float)((double)xcx * v1x + (double)xcy * v1y);
    projs[row * 2 + 1] = (float)((double)xcx * v2x + (double)xcy * v2y);
    rns[row] = rn;
}

// ---------------------------------------------------------------------------
// Fused transpose-casts: W [K,N] fp32 -> Wt [N,Kld] bf16 (zero-fill K..Kld,
// optional negation), 11 jobs + wesT build + gene cast, one launch.
// ---------------------------------------------------------------------------
struct TCJob {
    const float* src;
    us* dst;
    int K, N, Kld, neg, b0;
};
struct TC11 {
    TCJob j[11];
    int acc_end;
    const float* wa1_s;
    us* wesT_d;
    const float* gene_s;
    us* gene_d;
};

__global__ __launch_bounds__(256) void tcast_all(TC11 P) {
    __shared__ float tile[32][33];
    int b = blockIdx.x;
    if (b >= P.acc_end) {
        int lb = b - P.acc_end;
        if (lb < 64) {  // wesT: [512,32], t>=16 zero
            int idx = lb * 256 + threadIdx.x;
            int c = idx >> 5, t = idx & 31;
            P.wesT_d[idx] = (t < 16) ? f2bf(P.wa1_s[(size_t)(128 + t) * 512 + c]) : (us)0;
        } else {  // gene cast: [2048,64], c>=50 zero
            int idx = (lb - 64) * 256 + threadIdx.x;
            int r = idx >> 6, c = idx & 63;
            P.gene_d[idx] = (c < 50) ? f2bf(P.gene_s[r * 50 + c]) : (us)0;
        }
        return;
    }
    int ji = 0;
#pragma unroll
    for (int i = 1; i < 11; ++i)
        if (b >= P.j[i].b0) ji = i;
    const float* W = P.j[ji].src;
    us* Wt = P.j[ji].dst;
    int K = P.j[ji].K, N = P.j[ji].N, Kld = P.j[ji].Kld;
    float sgn = P.j[ji].neg ? -1.f : 1.f;
    int lb = b - P.j[ji].b0;
    int nbx = (N + 31) >> 5;
    int n0 = (lb % nbx) * 32, k0 = (lb / nbx) * 32;
    int tx = threadIdx.x & 31, ty = threadIdx.x >> 5;
#pragma unroll
    for (int p = 0; p < 4; ++p) {
        int k = k0 + ty + p * 8;
        tile[ty + p * 8][tx] = (k < K && n0 + tx < N) ? W[(size_t)k * N + n0 + tx] : 0.f;
    }
    __syncthreads();
#pragma unroll
    for (int p = 0; p < 4; ++p) {
        int n = n0 + ty + p * 8;
        if (n < N && k0 + tx < Kld)
            Wt[(size_t)n * Kld + k0 + tx] = f2bf(sgn * tile[tx][ty + p * 8]);
    }
}

// ---------------------------------------------------------------------------
// Batched bf16 MFMA GEMM (job table, up to 4 independent jobs per launch).
// residH: row-broadcast-by-8 residual with sign hs (v += hs*residH[row>>3]).
// Split-K: pointers pre-offset, nkt = sub-K/64.
// ---------------------------------------------------------------------------
struct GJob {
    const us* A;
    const us* Bt;
    const float* bias;
    const float* resid;
    const float* residH;
    float* outF;
    us* outB;
    us* outB2;
    us* outB3;
    float hs;
    int M, Kstride, nkt, N, Nout, b0;
};
struct GJobs {
    GJob j[4];
    int nj;
};

__global__ __launch_bounds__(256) void gemm_bf16_kernel(GJobs P) {
    __shared__ us As[2][128 * 64];
    __shared__ us Bs[2][128 * 64];
    int b = blockIdx.x;
    int ji = 0;
#pragma unroll
    for (int i = 1; i < 4; ++i)
        if (i < P.nj && b >= P.j[i].b0) ji = i;
    const us* A = P.j[ji].A;
    const us* Bt = P.j[ji].Bt;
    int Kst = P.j[ji].Kstride, nkt = P.j[ji].nkt;
    int Nn = P.j[ji].N, Nout = P.j[ji].Nout;
    int lb = b - P.j[ji].b0;
    int ncol = Nn >> 7;
    int col0 = (lb % ncol) << 7, row0 = (lb / ncol) << 7;

    int tid = threadIdx.x;
    int lane = tid & 63;
    int w = tid >> 6;
    int wr = w >> 1, wc = w & 1;
    f4_t acc[4][4];
#pragma unroll
    for (int a = 0; a < 4; ++a)
#pragma unroll
        for (int bb = 0; bb < 4; ++bb) {
            acc[a][bb][0] = 0.f; acc[a][bb][1] = 0.f;
            acc[a][bb][2] = 0.f; acc[a][bb][3] = 0.f;
        }

    auto stage = [&](int buf, int kt) {
#pragma unroll
        for (int p = 0; p < 4; ++p) {
            int id = p * 256 + tid;          // 1024 chunks of 16B
            int r = id >> 3, cch = id & 7;
            int kc = cch ^ (r & 7);          // swizzled source chunk
            int wb = p * 256 + (tid & 192);  // wave-uniform LDS chunk base
            gload16(A + (size_t)(row0 + r) * Kst + kt + kc * 8, As[buf] + wb * 8);
            gload16(Bt + (size_t)(col0 + r) * Kst + kt + kc * 8, Bs[buf] + wb * 8);
        }
    };

    stage(0, 0);
    __syncthreads();  // drain prologue loads
    for (int t = 0; t < nkt; ++t) {
        int cur = t & 1;
        if (t + 1 < nkt) stage(cur ^ 1, (t + 1) << 6);  // prefetch next tile
#pragma unroll
        for (int kk = 0; kk < 2; ++kk) {
            bf8_t af[4], bfr[4];
            int kslot = kk * 4 + (lane >> 4);
#pragma unroll
            for (int mi = 0; mi < 4; ++mi) {
                int r = wr * 64 + mi * 16 + (lane & 15);
                af[mi] = *(const bf8_t*)((char*)As[cur] + r * 128 + ((kslot ^ (r & 7)) * 16));
            }
#pragma unroll
            for (int ni = 0; ni < 4; ++ni) {
                int r = wc * 64 + ni * 16 + (lane & 15);
                bfr[ni] = *(const bf8_t*)((char*)Bs[cur] + r * 128 + ((kslot ^ (r & 7)) * 16));
            }
#pragma unroll
            for (int mi = 0; mi < 4; ++mi)
#pragma unroll
                for (int ni = 0; ni < 4; ++ni)
                    acc[mi][ni] = __builtin_amdgcn_mfma_f32_16x16x32_bf16(
                        af[mi], bfr[ni], acc[mi][ni], 0, 0, 0);
        }
        __syncthreads();  // drains prefetch (vmcnt0) + protects buffer reuse
    }
    const float* bias = P.j[ji].bias;
    const float* resid = P.j[ji].resid;
    const float* residH = P.j[ji].residH;
    float hs = P.j[ji].hs;
    float* outF = P.j[ji].outF;
    us* outB = P.j[ji].outB;
    us* outB2 = P.j[ji].outB2;
    us* outB3 = P.j[ji].outB3;
    int cr = lane >> 4, cc = lane & 15;
#pragma unroll
    for (int mi = 0; mi < 4; ++mi)
#pragma unroll
        for (int ni = 0; ni < 4; ++ni) {
            int col = col0 + wc * 64 + ni * 16 + cc;
            if (col >= Nout) continue;
            float bv = bias ? bias[col] : 0.f;
#pragma unroll
            for (int j = 0; j < 4; ++j) {
                int row = row0 + wr * 64 + mi * 16 + cr * 4 + j;
                float v = acc[mi][ni][j] + bv;
                if (resid) v += resid[(size_t)row * Nout + col];
                if (residH) v = fmaf(hs, residH[(size_t)(row >> 3) * Nout + col], v);
                if (outF) outF[(size_t)row * Nout + col] = v;
                if (outB) {
                    if (outB2) {
                        int seg = col >> 9, cl = col & 511;
                        us* dst = seg == 0 ? outB : (seg == 1 ? outB2 : outB3);
                        dst[(size_t)row * 512 + cl] = f2bf(v);
                    } else {
                        outB[(size_t)row * Nout + col] = f2bf(v);
                    }
                }
            }
        }
}

// ---------------------------------------------------------------------------
// Frame MLP stage 1 -> u bf16: u[row,c] = 0.25*sum_f LN(gelu([frame,rn]@we1+be1))
// ---------------------------------------------------------------------------
__global__ __launch_bounds__(256) void frame_mlp1_kernel(const float* __restrict__ projs,
                                                         const float* __restrict__ rns,
                                                         const float* __restrict__ we1,
                                                         const float* __restrict__ be1,
                                                         us* __restrict__ u) {
    int row = blockIdx.x * 4 + (threadIdx.x >> 6);
    int lane = threadIdx.x & 63;
    float px = projs[row * 2], py = projs[row * 2 + 1], rn = rns[row];
    int c0 = lane, c1 = lane + 64;
    float w10a = we1[c0], w11a = we1[128 + c0], w12a = we1[256 + c0], b1a = be1[c0];
    float w10b = we1[c1], w11b = we1[128 + c1], w12b = we1[256 + c1], b1b = be1[c1];
    float acc0 = 0.f, acc1 = 0.f;
    const float opsx[4] = {-1.f, -1.f, 1.f, 1.f};
    const float opsy[4] = {-1.f, 1.f, -1.f, 1.f};
#pragma unroll
    for (int f = 0; f < 4; ++f) {
        float fx = opsx[f] * px, fy = opsy[f] * py;
        float h0 = gelu_f(fmaf(fx, w10a, fmaf(fy, w11a, fmaf(rn, w12a, b1a))));
        float h1 = gelu_f(fmaf(fx, w10b, fmaf(fy, w11b, fmaf(rn, w12b, b1b))));
        float s = wsum(h0 + h1);
        float ss = wsum(fmaf(h0, h0, h1 * h1));
        float mean = s * (1.f / 128.f);
        float var = ss * (1.f / 128.f) - mean * mean;
        float rs = rsqrtf(var + 1e-5f);
        acc0 += (h0 - mean) * rs;
        acc1 += (h1 - mean) * rs;
    }
    u[(size_t)row * 128 + c0] = f2bf(0.25f * acc0);
    u[(size_t)row * 128 + c1] = f2bf(0.25f * acc1);
}

// ---------------------------------------------------------------------------
// Fused logits + softmax + context aggregation. qpb already holds
// qp+ba1-gep[n] (folded in the qp GEMM epilogue) -> no qmg staging, no gepb;
// qp rows read straight from global (8 rows/block, L1-resident).
// ---------------------------------------------------------------------------
__global__ __launch_bounds__(256) void logits_fused_kernel(
    const us* __restrict__ qpb,     // qp+ba1-gep bf16 [16384,512]
    const float* __restrict__ kgf,  // kp+gep fp32 [16384,512]
    const us* __restrict__ edgeb,   // bf16 [2048][16][128] (+32 pad at end)
    const us* __restrict__ wesT,    // bf16 [512,32], k=16..31 zero
    const int* __restrict__ nbr,
    const float* __restrict__ wa2,
    const float* __restrict__ ba2,
    const us* __restrict__ v2b,     // v bf16 [2048,512] (h*64+t)
    us* __restrict__ scec) {
    __shared__ us Es[2048 + 32];  // 4.2 KB: edge rows (m*8+h) x 16, 32B stride
    __shared__ float wa2s[512];   // 2 KB
    __shared__ float lgs[128];
    __shared__ float attn[128];
    __shared__ float sinv[8];
    __shared__ int jns[16];
    int n = blockIdx.x, tid = threadIdx.x;
    int lane = tid & 63;
    float swv = 0.f;
#pragma unroll
    for (int i = 0; i < 8; ++i) swv += wa2[lane + 64 * i];
    float sw = wsum(swv);
    float ba2v = ba2[0];
    {
        const uint* s2 = (const uint*)(edgeb + (size_t)n * 2048);
        uint* d2 = (uint*)Es;
        for (int i = tid; i < 1040; i += 256) d2[i] = s2[i];
        for (int i = tid; i < 512; i += 256) wa2s[i] = wa2[i];
        if (tid < 16) jns[tid] = nbr[n * 16 + tid];
    }
    __syncthreads();

    int cc = lane & 15, cr = lane >> 4;
    int w = tid >> 6;
#pragma unroll
    for (int mt = 0; mt < 2; ++mt) {
        int mh = w * 32 + mt * 16 + cc;
        int m = mh >> 3, h = mh & 7;
        int j8h = jns[m] * 8 + h;
        const float* kgrow = kgf + (size_t)j8h * 512;
        const us* qrow = qpb + ((size_t)n * 8 + h) * 512;
        bf8_t bfr = *(const bf8_t*)((const char*)Es + mh * 32 + cr * 16);
        f2_t s2v = {0.f, 0.f}, ss2 = {0.f, 0.f}, sd2 = {0.f, 0.f};
#pragma unroll 4
        for (int ct = 0; ct < 32; ++ct) {
            int chb = ct * 16 + cr * 4;  // this lane's 4 channels
            bf8_t af = *(const bf8_t*)(wesT + (ct * 16 + cc) * 32 + cr * 8);
            f4_t z = {0.f, 0.f, 0.f, 0.f};
            f4_t ep = __builtin_amdgcn_mfma_f32_16x16x32_bf16(af, bfr, z, 0, 0, 0);
            float4 k4 = *(const float4*)(kgrow + chb);
            uint2 qp4 = *(const uint2*)(qrow + chb);
            float4 w4 = *(const float4*)(wa2s + chb);
            f2_t ep01 = {ep[0], ep[1]}, ep23 = {ep[2], ep[3]};
            f2_t q01 = {BF_LO(qp4.x), BF_HI(qp4.x)};
            f2_t q23 = {BF_LO(qp4.y), BF_HI(qp4.y)};
            f2_t k01 = {k4.x, k4.y};
            f2_t k23 = {k4.z, k4.w};
            f2_t g01 = gelu2(ep01 + q01 + k01);
            f2_t g23 = gelu2(ep23 + q23 + k23);
            s2v += g01;
            s2v += g23;
            ss2 = g01 * g01 + ss2;
            ss2 = g23 * g23 + ss2;
            f2_t w01 = {w4.x, w4.y}, w23 = {w4.z, w4.w};
            sd2 = g01 * w01 + sd2;
            sd2 = g23 * w23 + sd2;
        }
        float s = s2v.x + s2v.y, ss = ss2.x + ss2.y, sd = sd2.x + sd2.y;
        s += __shfl_xor(s, 16, 64);
        s += __shfl_xor(s, 32, 64);
        ss += __shfl_xor(ss, 16, 64);
        ss += __shfl_xor(ss, 32, 64);
        sd += __shfl_xor(sd, 16, 64);
        sd += __shfl_xor(sd, 32, 64);
        if (cr == 0) {
            float mean = s * (1.f / 512.f);
            float var = ss * (1.f / 512.f) - mean * mean;
            lgs[mh] = (sd - mean * sw) * rsqrtf(var + 1e-5f) + ba2v;
        }
    }
    __syncthreads();
    if (tid < 128) {
        int h = tid & 7;
        float mx = lgs[h];
#pragma unroll
        for (int mm = 1; mm < 16; ++mm) mx = fmaxf(mx, lgs[mm * 8 + h]);
        attn[tid] = __expf(lgs[tid] - mx);
    }
    __syncthreads();
    if (tid < 8) {
        float se = 0.f;
#pragma unroll
        for (int mm = 0; mm < 16; ++mm) se += attn[mm * 8 + tid];
        sinv[tid] = 1.f / se;
    }
    __syncthreads();
    for (int c = tid; c < 640; c += 256) {
        float acc = 0.f;
        int h;
        if (c < 512) {
            h = c >> 6;
            int t = c & 63;
#pragma unroll
            for (int m = 0; m < 16; ++m)
                acc = fmaf(attn[m * 8 + h], b2f(v2b[(size_t)jns[m] * 512 + h * 64 + t]), acc);
        } else {
            int d = c - 512;
            h = d >> 4;
            int t = d & 15;
#pragma unroll
            for (int m = 0; m < 16; ++m)
                acc = fmaf(attn[m * 8 + h], b2f(Es[m * 128 + h * 16 + t]), acc);
        }
        scec[(size_t)n * 640 + c] = f2bf(acc * sinv[h]);
    }
}

// ---------------------------------------------------------------------------
extern "C" void kernel_launch(void* const* d_in, const int* in_sizes, int n_in,
                              void* d_out, int out_size, void* d_ws, size_t ws_size,
                              hipStream_t stream) {
    const float* gene_exp = (const float*)d_in[0];
    const float* token_embs = (const float*)d_in[1];
    const float* coords = (const float*)d_in[2];
    const int* nbr = (const int*)d_in[3];
    const float* w_qkv = (const float*)d_in[4];
    const float* b_qkv = (const float*)d_in[5];
    const float* wa1 = (const float*)d_in[6];
    const float* ba1 = (const float*)d_in[7];
    const float* wa2 = (const float*)d_in[8];
    const float* ba2 = (const float*)d_in[9];
    const float* we1 = (const float*)d_in[10];
    const float* be1 = (const float*)d_in[11];
    const float* we2 = (const float*)d_in[12];
    const float* be2 = (const float*)d_in[13];
    const float* wo1 = (const float*)d_in[14];
    const float* bo1 = (const float*)d_in[15];
    const float* wo2 = (const float*)d_in[16];
    const float* bo2 = (const float*)d_in[17];
    const float* wm1 = (const float*)d_in[18];
    const float* bm1 = (const float*)d_in[19];
    const float* wm2 = (const float*)d_in[20];
    const float* bm2 = (const float*)d_in[21];
    const float* wg1 = (const float*)d_in[22];
    const float* bg1 = (const float*)d_in[23];
    const float* wg2 = (const float*)d_in[24];
    const float* bg2 = (const float*)d_in[25];

    float* out = (float*)d_out;
    float* gene_out = out;             // [2048, 50]
    float* tok_out = out + 2048 * 50;  // [2048, 512]

    float* ws = (float*)d_ws;
    size_t o = 0;
    auto alloc = [&](size_t nf) {
        float* p = ws + o;
        o += nf;
        return p;
    };
    us* x_ln_bf = (us*)alloc((size_t)2048 * 512 / 2);
    us* q2b = (us*)alloc((size_t)16384 * 64 / 2);
    us* k2b = (us*)alloc((size_t)16384 * 64 / 2);
    us* v2b = (us*)alloc((size_t)2048 * 512 / 2);
    us* qpb = (us*)alloc((size_t)16384 * 512 / 2);
    float* gepn = alloc((size_t)2048 * 512);  // holds NEGATED gep (fp32)
    us* edgeb = (us*)alloc(((size_t)2048 * 2048 + 32) / 2);
    us* scec_bf = (us*)alloc((size_t)2048 * 640 / 2);
    us* buf1_bf = (us*)alloc((size_t)2048 * 512 / 2);
    float* buf2 = alloc((size_t)2048 * 2048);
    us* buf2_bf = (us*)alloc((size_t)2048 * 2048 / 2);
    float* tok1 = alloc((size_t)2048 * 512);
    us* tok1_bf = (us*)alloc((size_t)2048 * 512 / 2);
    us* tokout_bf = (us*)alloc((size_t)2048 * 512 / 2);
    us* u_bf = (us*)alloc((size_t)32768 * 128 / 2);
    float* projs = alloc((size_t)32768 * 2);
    float* rns = alloc((size_t)32768);
    us* gene_bf = (us*)alloc((size_t)2048 * 64 / 2);
    // 32MB shared region: kgf (fp32 kg table, steps 4-5) aliases pk4 (steps 6+)
    float* shared32 = alloc((size_t)16384 * 512);
    float* kgf = shared32;
    float* pk4 = shared32;
    us* qkvT = (us*)alloc((size_t)1536 * 512 / 2);
    us* wa1qT = (us*)alloc((size_t)512 * 64 / 2);
    us* wa1kT = (us*)alloc((size_t)512 * 64 / 2);
    us* wa1gT = (us*)alloc((size_t)512 * 64 / 2);
    us* we2T = (us*)alloc((size_t)128 * 128 / 2);
    us* wo1T = (us*)alloc((size_t)512 * 640 / 2);
    us* wo2T = (us*)alloc((size_t)512 * 512 / 2);
    us* wm1T = (us*)alloc((size_t)2048 * 512 / 2);
    us* wm2T = (us*)alloc((size_t)512 * 2048 / 2);
    us* wg1T = (us*)alloc((size_t)512 * 512 / 2);
    us* wg2T = (us*)alloc((size_t)128 * 512 / 2);
    us* wesT = (us*)alloc((size_t)512 * 32 / 2);
    if (o * sizeof(float) > ws_size) return;  // ~136 MB required

    auto mkjob = [](const us* A, const us* Bt, const float* bias, const float* resid,
                    const float* residH, float hs, float* outF, us* outB, us* outB2,
                    us* outB3, int M, int Kstride, int nkt, int N, int Nout, int b0) {
        GJob j;
        j.A = A; j.Bt = Bt; j.bias = bias; j.resid = resid; j.residH = residH;
        j.hs = hs; j.outF = outF; j.outB = outB; j.outB2 = outB2; j.outB3 = outB3;
        j.M = M; j.Kstride = Kstride; j.nkt = nkt; j.N = N; j.Nout = Nout; j.b0 = b0;
        return j;
    };
    auto G1 = [&](const us* A, const us* Bt, const float* bias, const float* resid,
                  float* outF, us* outB, int M, int K, int N, int Nout) {
        GJobs P;
        P.nj = 1;
        P.j[0] = mkjob(A, Bt, bias, resid, nullptr, 1.f, outF, outB, nullptr, nullptr,
                       M, K, K >> 6, N, Nout, 0);
        gemm_bf16_kernel<<<(N / 128) * (M / 128), 256, 0, stream>>>(P);
    };
    // split-K=2 over K (halves of K/2 each), partials in pk4
    auto Gsk2 = [&](const us* A, const us* Bt, int M, int K, int N) {
        GJobs P;
        P.nj = 2;
        int half = K >> 1;
        int blk = (N / 128) * (M / 128);
        P.j[0] = mkjob(A, Bt, nullptr, nullptr, nullptr, 1.f, pk4, nullptr, nullptr,
                       nullptr, M, K, half >> 6, N, N, 0);
        P.j[1] = mkjob(A + half, Bt + half, nullptr, nullptr, nullptr, 1.f,
                       pk4 + 1048576, nullptr, nullptr, nullptr, M, K, half >> 6, N, N,
                       blk);
        gemm_bf16_kernel<<<2 * blk, 256, 0, stream>>>(P);
    };

    // 0. weight transpose-casts + wesT + gene cast (one launch)
    hipMemsetAsync(wg2T, 0, (size_t)128 * 512 * 2, stream);  // pad rows 50..127
    {
        TC11 P;
        auto set = [&](int i, const float* s, us* d, int K, int N, int Kld, int neg,
                       int& acc) {
            P.j[i] = {s, d, K, N, Kld, neg, acc};
            acc += ((N + 31) / 32) * ((Kld + 31) / 32);
        };
        int acc = 0;
        set(0, w_qkv, qkvT, 512, 1536, 512, 0, acc);
        set(1, wa1, wa1qT, 64, 512, 64, 0, acc);
        set(2, wa1 + 64 * 512, wa1kT, 64, 512, 64, 0, acc);
        set(3, we2, we2T, 128, 128, 128, 0, acc);
        set(4, wo1, wo1T, 640, 512, 640, 0, acc);
        set(5, wo2, wo2T, 512, 512, 512, 0, acc);
        set(6, wm1, wm1T, 512, 2048, 512, 0, acc);
        set(7, wm2, wm2T, 2048, 512, 2048, 0, acc);
        set(8, wg1, wg1T, 512, 512, 512, 0, acc);
        set(9, wa1 + 144 * 512, wa1gT, 50, 512, 64, 1, acc);  // NEGATED, K-pad 64
        set(10, wg2, wg2T, 512, 50, 512, 0, acc);             // rows 50.. = memset 0
        P.acc_end = acc;
        P.wa1_s = wa1;
        P.wesT_d = wesT;
        P.gene_s = gene_exp;
        P.gene_d = gene_bf;
        tcast_all<<<acc + 64 + 512, 256, 0, stream>>>(P);
    }

    // 1. LN(token_embs)->bf16 + frame projections (one launch)
    lnproj_kernel<<<2048 + 128, 256, 0, stream>>>(token_embs, x_ln_bf, coords, nbr,
                                                  projs, rns);
    // 2. frame MLP stage 1 -> u_bf
    frame_mlp1_kernel<<<8192, 256, 0, stream>>>(projs, rns, we1, be1, u_bf);
    // 3. BATCH{qkv(split q|k|v), gepn=-gene@wa1g}: 192+64 = 256 blocks
    {
        GJobs P;
        P.nj = 2;
        P.j[0] = mkjob(x_ln_bf, qkvT, b_qkv, nullptr, nullptr, 1.f, nullptr, q2b, k2b,
                       v2b, 2048, 512, 8, 1536, 1536, 0);
        P.j[1] = mkjob(gene_bf, wa1gT, nullptr, nullptr, nullptr, 1.f, gepn, nullptr,
                       nullptr, nullptr, 2048, 64, 1, 512, 512, 192);
        gemm_bf16_kernel<<<256, 256, 0, stream>>>(P);
    }
    // 4. BATCH{qp(+ba1-gep), kg(+gep, fp32 out), edge}: 512+512+256 = 1280 blocks
    {
        GJobs P;
        P.nj = 3;
        P.j[0] = mkjob(q2b, wa1qT, ba1, nullptr, gepn, 1.f, nullptr, qpb, nullptr,
                       nullptr, 16384, 64, 1, 512, 512, 0);
        P.j[1] = mkjob(k2b, wa1kT, nullptr, nullptr, gepn, -1.f, kgf, nullptr, nullptr,
                       nullptr, 16384, 64, 1, 512, 512, 512);
        P.j[2] = mkjob(u_bf, we2T, be2, nullptr, nullptr, 1.f, nullptr, edgeb, nullptr,
                       nullptr, 32768, 128, 2, 128, 128, 1024);
        gemm_bf16_kernel<<<1280, 256, 0, stream>>>(P);
    }
    // 5. fused logits + softmax + aggregation -> scec bf16
    logits_fused_kernel<<<2048, 256, 0, stream>>>(qpb, kgf, edgeb, wesT, nbr, wa2, ba2,
                                                  v2b, scec_bf);
    // 6. ctx = mlp2(scec, wo1, wo2); tok1 = token_embs + ctx
    Gsk2(scec_bf, wo1T, 2048, 640, 512);
    combine2ln_kernel<<<2048, 256, 0, stream>>>(pk4, bo1, buf1_bf);
    Gsk2(buf1_bf, wo2T, 2048, 512, 512);
    combine2_kernel<<<4096, 256, 0, stream>>>(pk4, bo2, token_embs, tok1, tok1_bf);
    // 7. tok2 = tok1 + mlp2(tok1, wm1, wm2) -> d_out tok section
    G1(tok1_bf, wm1T, bm1, nullptr, buf2, nullptr, 2048, 512, 2048, 2048);
    act_ln_kernel<<<2048, 256, 0, stream>>>(nullptr, buf2_bf, buf2, 2048, 1);
    {
        // wm2 split-K=4 as one batched launch (4x64 = 256 blocks), fp32 partials
        GJobs P;
        P.nj = 4;
#pragma unroll
        for (int s = 0; s < 4; ++s)
            P.j[s] = mkjob(buf2_bf + s * 512, wm2T + s * 512, nullptr, nullptr, nullptr,
                           1.f, pk4 + (size_t)s * 1048576, nullptr, nullptr, nullptr,
                           2048, 2048, 8, 512, 512, s * 64);
        gemm_bf16_kernel<<<256, 256, 0, stream>>>(P);
        wm2_combine<<<4096, 256, 0, stream>>>(pk4, bm2, tok1, tok_out, tokout_bf);
    }
    // 8. gene_out = mlp2(tok2, wg1, wg2)
    Gsk2(tokout_bf, wg1T, 2048, 512, 512);
    combine2ln_kernel<<<2048, 256, 0, stream>>>(pk4, bg1, buf1_bf);
    {
        // wg2 split-K=4: 4x16 = 64 blocks, partials [2048,50] each
        GJobs P;
        P.nj = 4;
#pragma unroll
        for (int s = 0; s < 4; ++s)
            P.j[s] = mkjob(buf1_bf + s * 128, wg2T + s * 128, nullptr, nullptr, nullptr,
                           1.f, pk4 + (size_t)s * 102400, nullptr, nullptr, nullptr,
                           2048, 512, 2, 128, 50, s * 16);
        gemm_bf16_kernel<<<64, 256, 0, stream>>>(P);
        wg2_combine<<<400, 256, 0, stream>>>(pk4, bg2, gene_out);
    }
}

// Round 16
// 332.660 us; speedup vs baseline: 1.1648x; 1.1648x over previous
//
#include <hip/hip_runtime.h>
#include <math.h>

// Problem constants
#define NN 2048
#define MM 16
#define DD 512
#define DE 128
#define HH 8
#define GG 50
#define DH 64
#define DEH 16

typedef __attribute__((ext_vector_type(8))) short bf8_t;   // 8 bf16 = 4 VGPRs
typedef __attribute__((ext_vector_type(4))) float f4_t;    // MFMA accumulator
typedef __attribute__((ext_vector_type(2))) float f2_t;    // packed f32 pair
typedef unsigned short us;

// Async global->LDS 16B copy. LDS dest must be wave-uniform base; HW writes
// base + lane*16. Global src is per-lane.
__device__ __forceinline__ void gload16(const us* g, us* l) {
    __builtin_amdgcn_global_load_lds(
        (const __attribute__((address_space(1))) unsigned int*)g,
        (__attribute__((address_space(3))) unsigned int*)l, 16, 0, 0);
}

// Branchless tanh-approx GELU (max |err| vs erf-gelu ~3e-3)
__device__ __forceinline__ float gelu_f(float x) {
    float u = 1.5957691216f * fmaf(0.044715f * x, x * x, x);
    u = fminf(fmaxf(u, -30.f), 30.f);
    float e = __expf(u);
    float t = fmaf(-2.f, __builtin_amdgcn_rcpf(e + 1.f), 1.f);  // tanh(u/2)
    float hx = 0.5f * x;
    return fmaf(hx, t, hx);
}

// Packed-pair gelu, clamp-free (exp overflow saturates to the right limits).
__device__ __forceinline__ f2_t gelu2(f2_t x) {
    f2_t u = ((x * 0.044715f) * (x * x) + x) * 1.5957691216f;
    f2_t e1;
    e1.x = __expf(u.x) + 1.f;
    e1.y = __expf(u.y) + 1.f;
    f2_t r;
    r.x = __builtin_amdgcn_rcpf(e1.x);
    r.y = __builtin_amdgcn_rcpf(e1.y);
    f2_t t = r * (-2.f) + 1.f;
    f2_t hx = x * 0.5f;
    return hx * t + hx;
}

__device__ __forceinline__ float wsum(float v) {
#pragma unroll
    for (int o = 32; o; o >>= 1) v += __shfl_xor(v, o, 64);
    return v;
}

__device__ __forceinline__ us f2bf(float x) {
    union { float f; unsigned int u; } v;
    v.f = x;
    unsigned int r = v.u + 0x7FFFu + ((v.u >> 16) & 1u);  // RNE
    return (us)(r >> 16);
}

__device__ __forceinline__ float bfu(unsigned int u) {
    union { unsigned int x; float f; } v;
    v.x = u;
    return v.f;
}
#define BF_LO(u) bfu((u) << 16)
#define BF_HI(u) bfu((u) & 0xFFFF0000u)
__device__ __forceinline__ float b2f(us u) { return bfu((unsigned int)u << 16); }

// ---------------------------------------------------------------------------
// Row-wise (optional GELU) + LayerNorm. Writes fp32 and/or bf16 output.
// ---------------------------------------------------------------------------
__global__ __launch_bounds__(256) void act_ln_kernel(float* __restrict__ outF,
                                                     us* __restrict__ outB,
                                                     const float* __restrict__ x,
                                                     int C, int do_gelu) {
    int row = blockIdx.x, tid = threadIdx.x;
    int nv = C >> 8;  // C is 512 or 2048
    float v[8];
    float s = 0.f, ss = 0.f;
    for (int i = 0; i < nv; ++i) {
        float val = x[(size_t)row * C + tid + (i << 8)];
        if (do_gelu) val = gelu_f(val);
        v[i] = val;
        s += val;
        ss += val * val;
    }
    __shared__ float red[4][2];
    s = wsum(s);
    ss = wsum(ss);
    int wid = tid >> 6, lane = tid & 63;
    if (lane == 0) { red[wid][0] = s; red[wid][1] = ss; }
    __syncthreads();
    s = red[0][0] + red[1][0] + red[2][0] + red[3][0];
    ss = red[0][1] + red[1][1] + red[2][1] + red[3][1];
    float mean = s / (float)C;
    float var = ss / (float)C - mean * mean;
    float rs = rsqrtf(var + 1e-5f);
    for (int i = 0; i < nv; ++i) {
        float y = (v[i] - mean) * rs;
        size_t idx = (size_t)row * C + tid + (i << 8);
        if (outF) outF[idx] = y;
        if (outB) outB[idx] = f2bf(y);
    }
}

// ---------------------------------------------------------------------------
// Split-K=2 combine + bias + GELU + LN -> bf16 (row-wise, C=512).
// ---------------------------------------------------------------------------
__global__ __launch_bounds__(256) void combine2ln_kernel(const float* __restrict__ pk,
                                                         const float* __restrict__ bias,
                                                         us* __restrict__ outB) {
    int row = blockIdx.x, tid = threadIdx.x;
    size_t b = (size_t)row * 512;
    float v0 = gelu_f(pk[b + tid] + pk[1048576 + b + tid] + bias[tid]);
    float v1 = gelu_f(pk[b + 256 + tid] + pk[1048576 + b + 256 + tid] + bias[256 + tid]);
    __shared__ float red[4][2];
    float s = wsum(v0 + v1);
    float ss = wsum(fmaf(v0, v0, v1 * v1));
    int wid = tid >> 6, lane = tid & 63;
    if (lane == 0) { red[wid][0] = s; red[wid][1] = ss; }
    __syncthreads();
    s = red[0][0] + red[1][0] + red[2][0] + red[3][0];
    ss = red[0][1] + red[1][1] + red[2][1] + red[3][1];
    float mean = s * (1.f / 512.f);
    float var = ss * (1.f / 512.f) - mean * mean;
    float rs = rsqrtf(var + 1e-5f);
    outB[b + tid] = f2bf((v0 - mean) * rs);
    outB[b + 256 + tid] = f2bf((v1 - mean) * rs);
}

// ---------------------------------------------------------------------------
// Split-K=2 combine + bias + resid -> fp32 + bf16 (elementwise, 2048x512).
// ---------------------------------------------------------------------------
__global__ __launch_bounds__(256) void combine2_kernel(const float* __restrict__ pk,
                                                       const float* __restrict__ bias,
                                                       const float* __restrict__ resid,
                                                       float* __restrict__ outF,
                                                       us* __restrict__ outB) {
    int idx = blockIdx.x * 256 + threadIdx.x;
    float v = pk[idx] + pk[idx + 1048576] + bias[idx & 511] + resid[idx];
    outF[idx] = v;
    outB[idx] = f2bf(v);
}

// ---------------------------------------------------------------------------
// Split-K=4 combine for wm2: tok_out = sum4 + bias + resid, fp32 + bf16.
// ---------------------------------------------------------------------------
__global__ __launch_bounds__(256) void wm2_combine(const float* __restrict__ pk,
                                                   const float* __restrict__ bias,
                                                   const float* __restrict__ resid,
                                                   float* __restrict__ outF,
                                                   us* __restrict__ outB) {
    int idx = blockIdx.x * 256 + threadIdx.x;
    float v = pk[idx] + pk[idx + 1048576] + pk[idx + 2097152] + pk[idx + 3145728] +
              bias[idx & 511] + resid[idx];
    outF[idx] = v;
    outB[idx] = f2bf(v);
}

// ---------------------------------------------------------------------------
// Split-K=4 combine for wg2: gene_out = sum4 + bias (2048x50 fp32).
// ---------------------------------------------------------------------------
__global__ __launch_bounds__(256) void wg2_combine(const float* __restrict__ pk,
                                                   const float* __restrict__ bias,
                                                   float* __restrict__ outF) {
    int idx = blockIdx.x * 256 + threadIdx.x;
    if (idx >= 102400) return;
    float v = pk[idx] + pk[idx + 102400] + pk[idx + 204800] + pk[idx + 307200] +
              bias[idx % 50];
    outF[idx] = v;
}

// ---------------------------------------------------------------------------
// Fused LN(token_embs)->bf16 (blocks 0..2047) + frame projections (blocks
// 2048..2175; 16 nodes per block).
// ---------------------------------------------------------------------------
__global__ __launch_bounds__(256) void lnproj_kernel(const float* __restrict__ te,
                                                     us* __restrict__ x_ln_bf,
                                                     const float* __restrict__ coords,
                                                     const int* __restrict__ nbr,
                                                     float* __restrict__ projs,
                                                     float* __restrict__ rns) {
    int tid = threadIdx.x;
    if (blockIdx.x < 2048) {
        int row = blockIdx.x;
        float v0 = te[(size_t)row * 512 + tid];
        float v1 = te[(size_t)row * 512 + 256 + tid];
        __shared__ float red[4][2];
        float s = wsum(v0 + v1);
        float ss = wsum(fmaf(v0, v0, v1 * v1));
        int wid = tid >> 6, lane = tid & 63;
        if (lane == 0) { red[wid][0] = s; red[wid][1] = ss; }
        __syncthreads();
        s = red[0][0] + red[1][0] + red[2][0] + red[3][0];
        ss = red[0][1] + red[1][1] + red[2][1] + red[3][1];
        float mean = s * (1.f / 512.f);
        float var = ss * (1.f / 512.f) - mean * mean;
        float rs = rsqrtf(var + 1e-5f);
        x_ln_bf[(size_t)row * 512 + tid] = f2bf((v0 - mean) * rs);
        x_ln_bf[(size_t)row * 512 + 256 + tid] = f2bf((v1 - mean) * rs);
        return;
    }
    int node = (blockIdx.x - 2048) * 16 + (tid >> 4);
    int m = tid & 15;
    float cx = coords[node * 2], cy = coords[node * 2 + 1];
    int j = nbr[node * 16 + m];
    float rx = coords[j * 2] - cx;
    float ry = coords[j * 2 + 1] - cy;
    float rn = sqrtf(rx * rx + ry * ry);
    float mx = rx, my = ry;
#pragma unroll
    for (int o = 8; o; o >>= 1) { mx += __shfl_xor(mx, o, 16); my += __shfl_xor(my, o, 16); }
    mx *= 0.0625f;
    my *= 0.0625f;
    float xcx = rx - mx, xcy = ry - my;
    float sxx = xcx * xcx, sxy = xcx * xcy, syy = xcy * xcy;
#pragma unroll
    for (int o = 8; o; o >>= 1) {
        sxx += __shfl_xor(sxx, o, 16);
        sxy += __shfl_xor(sxy, o, 16);
        syy += __shfl_xor(syy, o, 16);
    }
    double a = (double)sxx, b = (double)sxy, c = (double)syy;
    double diff = 0.5 * (a - c);
    double disc = sqrt(diff * diff + b * b);
    double l2 = 0.5 * (a + c) + disc;
    double v2x = b, v2y = l2 - a;
    double nn2 = sqrt(v2x * v2x + v2y * v2y);
    if (nn2 < 1e-30) { v2x = (a >= c) ? 1.0 : 0.0; v2y = 1.0 - v2x; nn2 = 1.0; }
    v2x /= nn2;
    v2y /= nn2;
    double v1x = -v2y, v1y = v2x;  // eigenvector of smaller eigenvalue
    int row = node * 16 + m;
    projs[row * 2] = (float)((double)xcx * v1x + (double)xcy * v1y);
    projs[row * 2 + 1] = (float)((double)xcx * v2x + (double)xcy * v2y);
    rns[row] = rn;
}

// ---------------------------------------------------------------------------
// Fused transpose-casts: W [K,N] fp32 -> Wt [N,Kld] bf16 (zero-fill K..Kld),
// 11 jobs + wesT build + gene cast, all in one launch.
// ---------------------------------------------------------------------------
struct TCJob {
    const float* src;
    us* dst;
    int K, N, Kld, b0;
};
struct TC11 {
    TCJob j[11];
    int acc_end;
    const float* wa1_s;
    us* wesT_d;
    const float* gene_s;
    us* gene_d;
};

__global__ __launch_bounds__(256) void tcast_all(TC11 P) {
    __shared__ float tile[32][33];
    int b = blockIdx.x;
    if (b >= P.acc_end) {
        int lb = b - P.acc_end;
        if (lb < 64) {  // wesT: [512,32], t>=16 zero
            int idx = lb * 256 + threadIdx.x;
            int c = idx >> 5, t = idx & 31;
            P.wesT_d[idx] = (t < 16) ? f2bf(P.wa1_s[(size_t)(128 + t) * 512 + c]) : (us)0;
        } else {  // gene cast: [2048,64], c>=50 zero
            int idx = (lb - 64) * 256 + threadIdx.x;
            int r = idx >> 6, c = idx & 63;
            P.gene_d[idx] = (c < 50) ? f2bf(P.gene_s[r * 50 + c]) : (us)0;
        }
        return;
    }
    int ji = 0;
#pragma unroll
    for (int i = 1; i < 11; ++i)
        if (b >= P.j[i].b0) ji = i;
    const float* W = P.j[ji].src;
    us* Wt = P.j[ji].dst;
    int K = P.j[ji].K, N = P.j[ji].N, Kld = P.j[ji].Kld;
    int lb = b - P.j[ji].b0;
    int nbx = (N + 31) >> 5;
    int n0 = (lb % nbx) * 32, k0 = (lb / nbx) * 32;
    int tx = threadIdx.x & 31, ty = threadIdx.x >> 5;
#pragma unroll
    for (int p = 0; p < 4; ++p) {
        int k = k0 + ty + p * 8;
        tile[ty + p * 8][tx] = (k < K && n0 + tx < N) ? W[(size_t)k * N + n0 + tx] : 0.f;
    }
    __syncthreads();
#pragma unroll
    for (int p = 0; p < 4; ++p) {
        int n = n0 + ty + p * 8;
        if (n < N && k0 + tx < Kld) Wt[(size_t)n * Kld + k0 + tx] = f2bf(tile[tx][ty + p * 8]);
    }
}

// ---------------------------------------------------------------------------
// Batched bf16 MFMA GEMM (job table, up to 4 independent jobs per launch).
// Split-K: pointers pre-offset, nkt = sub-K/64.
// ---------------------------------------------------------------------------
struct GJob {
    const us* A;
    const us* Bt;
    const float* bias;
    const float* resid;
    const float* residH;
    float* outF;
    us* outB;
    us* outB2;
    us* outB3;
    int M, Kstride, nkt, N, Nout, b0;
};
struct GJobs {
    GJob j[4];
    int nj;
};

__global__ __launch_bounds__(256) void gemm_bf16_kernel(GJobs P) {
    __shared__ us As[2][128 * 64];
    __shared__ us Bs[2][128 * 64];
    int b = blockIdx.x;
    int ji = 0;
#pragma unroll
    for (int i = 1; i < 4; ++i)
        if (i < P.nj && b >= P.j[i].b0) ji = i;
    const us* A = P.j[ji].A;
    const us* Bt = P.j[ji].Bt;
    int Kst = P.j[ji].Kstride, nkt = P.j[ji].nkt;
    int Nn = P.j[ji].N, Nout = P.j[ji].Nout;
    int lb = b - P.j[ji].b0;
    int ncol = Nn >> 7;
    int col0 = (lb % ncol) << 7, row0 = (lb / ncol) << 7;

    int tid = threadIdx.x;
    int lane = tid & 63;
    int w = tid >> 6;
    int wr = w >> 1, wc = w & 1;
    f4_t acc[4][4];
#pragma unroll
    for (int a = 0; a < 4; ++a)
#pragma unroll
        for (int bb = 0; bb < 4; ++bb) {
            acc[a][bb][0] = 0.f; acc[a][bb][1] = 0.f;
            acc[a][bb][2] = 0.f; acc[a][bb][3] = 0.f;
        }

    auto stage = [&](int buf, int kt) {
#pragma unroll
        for (int p = 0; p < 4; ++p) {
            int id = p * 256 + tid;          // 1024 chunks of 16B
            int r = id >> 3, cch = id & 7;
            int kc = cch ^ (r & 7);          // swizzled source chunk
            int wb = p * 256 + (tid & 192);  // wave-uniform LDS chunk base
            gload16(A + (size_t)(row0 + r) * Kst + kt + kc * 8, As[buf] + wb * 8);
            gload16(Bt + (size_t)(col0 + r) * Kst + kt + kc * 8, Bs[buf] + wb * 8);
        }
    };

    stage(0, 0);
    __syncthreads();  // drain prologue loads
    for (int t = 0; t < nkt; ++t) {
        int cur = t & 1;
        if (t + 1 < nkt) stage(cur ^ 1, (t + 1) << 6);  // prefetch next tile
#pragma unroll
        for (int kk = 0; kk < 2; ++kk) {
            bf8_t af[4], bfr[4];
            int kslot = kk * 4 + (lane >> 4);
#pragma unroll
            for (int mi = 0; mi < 4; ++mi) {
                int r = wr * 64 + mi * 16 + (lane & 15);
                af[mi] = *(const bf8_t*)((char*)As[cur] + r * 128 + ((kslot ^ (r & 7)) * 16));
            }
#pragma unroll
            for (int ni = 0; ni < 4; ++ni) {
                int r = wc * 64 + ni * 16 + (lane & 15);
                bfr[ni] = *(const bf8_t*)((char*)Bs[cur] + r * 128 + ((kslot ^ (r & 7)) * 16));
            }
#pragma unroll
            for (int mi = 0; mi < 4; ++mi)
#pragma unroll
                for (int ni = 0; ni < 4; ++ni)
                    acc[mi][ni] = __builtin_amdgcn_mfma_f32_16x16x32_bf16(
                        af[mi], bfr[ni], acc[mi][ni], 0, 0, 0);
        }
        __syncthreads();  // drains prefetch (vmcnt0) + protects buffer reuse
    }
    const float* bias = P.j[ji].bias;
    const float* resid = P.j[ji].resid;
    const float* residH = P.j[ji].residH;
    float* outF = P.j[ji].outF;
    us* outB = P.j[ji].outB;
    us* outB2 = P.j[ji].outB2;
    us* outB3 = P.j[ji].outB3;
    int cr = lane >> 4, cc = lane & 15;
#pragma unroll
    for (int mi = 0; mi < 4; ++mi)
#pragma unroll
        for (int ni = 0; ni < 4; ++ni) {
            int col = col0 + wc * 64 + ni * 16 + cc;
            if (col >= Nout) continue;
            float bv = bias ? bias[col] : 0.f;
#pragma unroll
            for (int j = 0; j < 4; ++j) {
                int row = row0 + wr * 64 + mi * 16 + cr * 4 + j;
                float v = acc[mi][ni][j] + bv;
                if (resid) v += resid[(size_t)row * Nout + col];
                if (residH) v += residH[(size_t)(row >> 3) * Nout + col];
                if (outF) outF[(size_t)row * Nout + col] = v;
                if (outB) {
                    if (outB2) {
                        int seg = col >> 9, cl = col & 511;
                        us* dst = seg == 0 ? outB : (seg == 1 ? outB2 : outB3);
                        dst[(size_t)row * 512 + cl] = f2bf(v);
                    } else {
                        outB[(size_t)row * Nout + col] = f2bf(v);
                    }
                }
            }
        }
}

// ---------------------------------------------------------------------------
// Frame MLP stage 1 -> u bf16: u[row,c] = 0.25*sum_f LN(gelu([frame,rn]@we1+be1))
// ---------------------------------------------------------------------------
__global__ __launch_bounds__(256) void frame_mlp1_kernel(const float* __restrict__ projs,
                                                         const float* __restrict__ rns,
                                                         const float* __restrict__ we1,
                                                         const float* __restrict__ be1,
                                                         us* __restrict__ u) {
    int row = blockIdx.x * 4 + (threadIdx.x >> 6);
    int lane = threadIdx.x & 63;
    float px = projs[row * 2], py = projs[row * 2 + 1], rn = rns[row];
    int c0 = lane, c1 = lane + 64;
    float w10a = we1[c0], w11a = we1[128 + c0], w12a = we1[256 + c0], b1a = be1[c0];
    float w10b = we1[c1], w11b = we1[128 + c1], w12b = we1[256 + c1], b1b = be1[c1];
    float acc0 = 0.f, acc1 = 0.f;
    const float opsx[4] = {-1.f, -1.f, 1.f, 1.f};
    const float opsy[4] = {-1.f, 1.f, -1.f, 1.f};
#pragma unroll
    for (int f = 0; f < 4; ++f) {
        float fx = opsx[f] * px, fy = opsy[f] * py;
        float h0 = gelu_f(fmaf(fx, w10a, fmaf(fy, w11a, fmaf(rn, w12a, b1a))));
        float h1 = gelu_f(fmaf(fx, w10b, fmaf(fy, w11b, fmaf(rn, w12b, b1b))));
        float s = wsum(h0 + h1);
        float ss = wsum(fmaf(h0, h0, h1 * h1));
        float mean = s * (1.f / 128.f);
        float var = ss * (1.f / 128.f) - mean * mean;
        float rs = rsqrtf(var + 1e-5f);
        acc0 += (h0 - mean) * rs;
        acc1 += (h1 - mean) * rs;
    }
    u[(size_t)row * 128 + c0] = f2bf(0.25f * acc0);
    u[(size_t)row * 128 + c1] = f2bf(0.25f * acc1);
}

// ---------------------------------------------------------------------------
// Fused logits + softmax + context aggregation. kg table FP32 -> the gather
// is one float4 load per ct-iter with zero unpack VALU. qmg staged in LDS.
// ---------------------------------------------------------------------------
__global__ __launch_bounds__(256) void logits_fused_kernel(
    const us* __restrict__ qpb,     // qp+ba1 bf16 [16384,512]
    const float* __restrict__ kgf,  // kp+gep fp32 [16384,512]
    const us* __restrict__ gepb,    // bf16 [2048,512]
    const us* __restrict__ edgeb,   // bf16 [2048][16][128] (+32 pad at end)
    const us* __restrict__ wesT,    // bf16 [512,32], k=16..31 zero
    const int* __restrict__ nbr,
    const float* __restrict__ wa2,
    const float* __restrict__ ba2,
    const us* __restrict__ v2b,     // v bf16 [2048,512] (h*64+t)
    us* __restrict__ scec) {
    __shared__ us Es[2048 + 32];  // 4.2 KB: edge rows (m*8+h) x 16, 32B stride
    __shared__ us qmg[8 * 520];   // 8.1 KB: (qp+ba1-gep[n]) bf16, padded rows
    __shared__ float wa2s[512];   // 2 KB
    __shared__ float lgs[128];
    __shared__ float attn[128];
    __shared__ float sinv[8];
    __shared__ int jns[16];
    int n = blockIdx.x, tid = threadIdx.x;
    int lane = tid & 63;
    float swv = 0.f;
#pragma unroll
    for (int i = 0; i < 8; ++i) swv += wa2[lane + 64 * i];
    float sw = wsum(swv);
    float ba2v = ba2[0];
    {
        const uint* s2 = (const uint*)(edgeb + (size_t)n * 2048);
        uint* d2 = (uint*)Es;
        for (int i = tid; i < 1040; i += 256) d2[i] = s2[i];
        const uint* s3 = (const uint*)(qpb + (size_t)n * 4096);
        const uint* s4 = (const uint*)(gepb + (size_t)n * 512);
        uint* d3 = (uint*)qmg;
        for (int i = tid; i < 2048; i += 256) {
            uint q = s3[i], g = s4[i & 255];
            float lo = BF_LO(q) - BF_LO(g), hi = BF_HI(q) - BF_HI(g);
            d3[(i >> 8) * 260 + (i & 255)] = ((uint)f2bf(hi) << 16) | (uint)f2bf(lo);
        }
        for (int i = tid; i < 512; i += 256) wa2s[i] = wa2[i];
        if (tid < 16) jns[tid] = nbr[n * 16 + tid];
    }
    __syncthreads();

    int cc = lane & 15, cr = lane >> 4;
    int w = tid >> 6;
#pragma unroll
    for (int mt = 0; mt < 2; ++mt) {
        int mh = w * 32 + mt * 16 + cc;
        int m = mh >> 3, h = mh & 7;
        int j8h = jns[m] * 8 + h;
        const float* kgrow = kgf + (size_t)j8h * 512;
        const us* qrow = qmg + h * 520;
        bf8_t bfr = *(const bf8_t*)((const char*)Es + mh * 32 + cr * 16);
        f2_t s2v = {0.f, 0.f}, ss2 = {0.f, 0.f}, sd2 = {0.f, 0.f};
#pragma unroll 4
        for (int ct = 0; ct < 32; ++ct) {
            int chb = ct * 16 + cr * 4;  // this lane's 4 channels
            bf8_t af = *(const bf8_t*)(wesT + (ct * 16 + cc) * 32 + cr * 8);
            f4_t z = {0.f, 0.f, 0.f, 0.f};
            f4_t ep = __builtin_amdgcn_mfma_f32_16x16x32_bf16(af, bfr, z, 0, 0, 0);
            float4 k4 = *(const float4*)(kgrow + chb);
            uint2 qp4 = *(const uint2*)(qrow + chb);
            float4 w4 = *(const float4*)(wa2s + chb);
            f2_t ep01 = {ep[0], ep[1]}, ep23 = {ep[2], ep[3]};
            f2_t q01 = {BF_LO(qp4.x), BF_HI(qp4.x)};
            f2_t q23 = {BF_LO(qp4.y), BF_HI(qp4.y)};
            f2_t k01 = {k4.x, k4.y};
            f2_t k23 = {k4.z, k4.w};
            f2_t g01 = gelu2(ep01 + q01 + k01);
            f2_t g23 = gelu2(ep23 + q23 + k23);
            s2v += g01;
            s2v += g23;
            ss2 = g01 * g01 + ss2;
            ss2 = g23 * g23 + ss2;
            f2_t w01 = {w4.x, w4.y}, w23 = {w4.z, w4.w};
            sd2 = g01 * w01 + sd2;
            sd2 = g23 * w23 + sd2;
        }
        float s = s2v.x + s2v.y, ss = ss2.x + ss2.y, sd = sd2.x + sd2.y;
        s += __shfl_xor(s, 16, 64);
        s += __shfl_xor(s, 32, 64);
        ss += __shfl_xor(ss, 16, 64);
        ss += __shfl_xor(ss, 32, 64);
        sd += __shfl_xor(sd, 16, 64);
        sd += __shfl_xor(sd, 32, 64);
        if (cr == 0) {
            float mean = s * (1.f / 512.f);
            float var = ss * (1.f / 512.f) - mean * mean;
            lgs[mh] = (sd - mean * sw) * rsqrtf(var + 1e-5f) + ba2v;
        }
    }
    __syncthreads();
    if (tid < 128) {
        int h = tid & 7;
        float mx = lgs[h];
#pragma unroll
        for (int mm = 1; mm < 16; ++mm) mx = fmaxf(mx, lgs[mm * 8 + h]);
        attn[tid] = __expf(lgs[tid] - mx);
    }
    __syncthreads();
    if (tid < 8) {
        float se = 0.f;
#pragma unroll
        for (int mm = 0; mm < 16; ++mm) se += attn[mm * 8 + tid];
        sinv[tid] = 1.f / se;
    }
    __syncthreads();
    for (int c = tid; c < 640; c += 256) {
        float acc = 0.f;
        int h;
        if (c < 512) {
            h = c >> 6;
            int t = c & 63;
#pragma unroll
            for (int m = 0; m < 16; ++m)
                acc = fmaf(attn[m * 8 + h], b2f(v2b[(size_t)jns[m] * 512 + h * 64 + t]), acc);
        } else {
            int d = c - 512;
            h = d >> 4;
            int t = d & 15;
#pragma unroll
            for (int m = 0; m < 16; ++m)
                acc = fmaf(attn[m * 8 + h], b2f(Es[m * 128 + h * 16 + t]), acc);
        }
        scec[(size_t)n * 640 + c] = f2bf(acc * sinv[h]);
    }
}

// ---------------------------------------------------------------------------
extern "C" void kernel_launch(void* const* d_in, const int* in_sizes, int n_in,
                              void* d_out, int out_size, void* d_ws, size_t ws_size,
                              hipStream_t stream) {
    const float* gene_exp = (const float*)d_in[0];
    const float* token_embs = (const float*)d_in[1];
    const float* coords = (const float*)d_in[2];
    const int* nbr = (const int*)d_in[3];
    const float* w_qkv = (const float*)d_in[4];
    const float* b_qkv = (const float*)d_in[5];
    const float* wa1 = (const float*)d_in[6];
    const float* ba1 = (const float*)d_in[7];
    const float* wa2 = (const float*)d_in[8];
    const float* ba2 = (const float*)d_in[9];
    const float* we1 = (const float*)d_in[10];
    const float* be1 = (const float*)d_in[11];
    const float* we2 = (const float*)d_in[12];
    const float* be2 = (const float*)d_in[13];
    const float* wo1 = (const float*)d_in[14];
    const float* bo1 = (const float*)d_in[15];
    const float* wo2 = (const float*)d_in[16];
    const float* bo2 = (const float*)d_in[17];
    const float* wm1 = (const float*)d_in[18];
    const float* bm1 = (const float*)d_in[19];
    const float* wm2 = (const float*)d_in[20];
    const float* bm2 = (const float*)d_in[21];
    const float* wg1 = (const float*)d_in[22];
    const float* bg1 = (const float*)d_in[23];
    const float* wg2 = (const float*)d_in[24];
    const float* bg2 = (const float*)d_in[25];

    float* out = (float*)d_out;
    float* gene_out = out;             // [2048, 50]
    float* tok_out = out + 2048 * 50;  // [2048, 512]

    float* ws = (float*)d_ws;
    size_t o = 0;
    auto alloc = [&](size_t nf) {
        float* p = ws + o;
        o += nf;
        return p;
    };
    us* x_ln_bf = (us*)alloc((size_t)2048 * 512 / 2);
    us* q2b = (us*)alloc((size_t)16384 * 64 / 2);
    us* k2b = (us*)alloc((size_t)16384 * 64 / 2);
    us* v2b = (us*)alloc((size_t)2048 * 512 / 2);
    us* qpb = (us*)alloc((size_t)16384 * 512 / 2);
    float* gep = alloc((size_t)2048 * 512);
    us* gepb = (us*)alloc((size_t)2048 * 512 / 2);
    us* edgeb = (us*)alloc(((size_t)2048 * 2048 + 32) / 2);
    us* scec_bf = (us*)alloc((size_t)2048 * 640 / 2);
    us* buf1_bf = (us*)alloc((size_t)2048 * 512 / 2);
    float* buf2 = alloc((size_t)2048 * 2048);
    us* buf2_bf = (us*)alloc((size_t)2048 * 2048 / 2);
    float* tok1 = alloc((size_t)2048 * 512);
    us* tok1_bf = (us*)alloc((size_t)2048 * 512 / 2);
    us* tokout_bf = (us*)alloc((size_t)2048 * 512 / 2);
    us* u_bf = (us*)alloc((size_t)32768 * 128 / 2);
    float* projs = alloc((size_t)32768 * 2);
    float* rns = alloc((size_t)32768);
    us* gene_bf = (us*)alloc((size_t)2048 * 64 / 2);
    // 32MB shared region: kgf (fp32 kg table, steps 4-5) aliases pk4 (steps 6+)
    float* shared32 = alloc((size_t)16384 * 512);
    float* kgf = shared32;
    float* pk4 = shared32;
    us* qkvT = (us*)alloc((size_t)1536 * 512 / 2);
    us* wa1qT = (us*)alloc((size_t)512 * 64 / 2);
    us* wa1kT = (us*)alloc((size_t)512 * 64 / 2);
    us* wa1gT = (us*)alloc((size_t)512 * 64 / 2);
    us* we2T = (us*)alloc((size_t)128 * 128 / 2);
    us* wo1T = (us*)alloc((size_t)512 * 640 / 2);
    us* wo2T = (us*)alloc((size_t)512 * 512 / 2);
    us* wm1T = (us*)alloc((size_t)2048 * 512 / 2);
    us* wm2T = (us*)alloc((size_t)512 * 2048 / 2);
    us* wg1T = (us*)alloc((size_t)512 * 512 / 2);
    us* wg2T = (us*)alloc((size_t)128 * 512 / 2);
    us* wesT = (us*)alloc((size_t)512 * 32 / 2);
    if (o * sizeof(float) > ws_size) return;  // ~136 MB required

    auto mkjob = [](const us* A, const us* Bt, const float* bias, const float* resid,
                    const float* residH, float* outF, us* outB, us* outB2, us* outB3,
                    int M, int Kstride, int nkt, int N, int Nout, int b0) {
        GJob j;
        j.A = A; j.Bt = Bt; j.bias = bias; j.resid = resid; j.residH = residH;
        j.outF = outF; j.outB = outB; j.outB2 = outB2; j.outB3 = outB3;
        j.M = M; j.Kstride = Kstride; j.nkt = nkt; j.N = N; j.Nout = Nout; j.b0 = b0;
        return j;
    };
    auto G1 = [&](const us* A, const us* Bt, const float* bias, const float* resid,
                  const float* residH, float* outF, us* outB, int M, int K, int N,
                  int Nout) {
        GJobs P;
        P.nj = 1;
        P.j[0] = mkjob(A, Bt, bias, resid, residH, outF, outB, nullptr, nullptr,
                       M, K, K >> 6, N, Nout, 0);
        gemm_bf16_kernel<<<(N / 128) * (M / 128), 256, 0, stream>>>(P);
    };
    // split-K=2 over K (halves of K/2 each), partials in pk4
    auto Gsk2 = [&](const us* A, const us* Bt, int M, int K, int N) {
        GJobs P;
        P.nj = 2;
        int half = K >> 1;
        int blk = (N / 128) * (M / 128);
        P.j[0] = mkjob(A, Bt, nullptr, nullptr, nullptr, pk4, nullptr, nullptr, nullptr,
                       M, K, half >> 6, N, N, 0);
        P.j[1] = mkjob(A + half, Bt + half, nullptr, nullptr, nullptr, pk4 + 1048576,
                       nullptr, nullptr, nullptr, M, K, half >> 6, N, N, blk);
        gemm_bf16_kernel<<<2 * blk, 256, 0, stream>>>(P);
    };

    // 0. weight transpose-casts + wesT + gene cast (one launch)
    hipMemsetAsync(wg2T, 0, (size_t)128 * 512 * 2, stream);  // pad rows 50..127
    {
        TC11 P;
        auto set = [&](int i, const float* s, us* d, int K, int N, int Kld, int& acc) {
            P.j[i] = {s, d, K, N, Kld, acc};
            acc += ((N + 31) / 32) * ((Kld + 31) / 32);
        };
        int acc = 0;
        set(0, w_qkv, qkvT, 512, 1536, 512, acc);
        set(1, wa1, wa1qT, 64, 512, 64, acc);
        set(2, wa1 + 64 * 512, wa1kT, 64, 512, 64, acc);
        set(3, we2, we2T, 128, 128, 128, acc);
        set(4, wo1, wo1T, 640, 512, 640, acc);
        set(5, wo2, wo2T, 512, 512, 512, acc);
        set(6, wm1, wm1T, 512, 2048, 512, acc);
        set(7, wm2, wm2T, 2048, 512, 2048, acc);
        set(8, wg1, wg1T, 512, 512, 512, acc);
        set(9, wa1 + 144 * 512, wa1gT, 50, 512, 64, acc);  // K-padded to 64
        set(10, wg2, wg2T, 512, 50, 512, acc);             // rows 50..127 = memset 0
        P.acc_end = acc;
        P.wa1_s = wa1;
        P.wesT_d = wesT;
        P.gene_s = gene_exp;
        P.gene_d = gene_bf;
        tcast_all<<<acc + 64 + 512, 256, 0, stream>>>(P);
    }

    // 1. LN(token_embs)->bf16 + frame projections (one launch)
    lnproj_kernel<<<2048 + 128, 256, 0, stream>>>(token_embs, x_ln_bf, coords, nbr,
                                                  projs, rns);
    // 2. frame MLP stage 1 -> u_bf
    frame_mlp1_kernel<<<8192, 256, 0, stream>>>(projs, rns, we1, be1, u_bf);
    // 3. BATCH{qkv(split q|k|v), gep}: 192+64 = 256 blocks
    {
        GJobs P;
        P.nj = 2;
        P.j[0] = mkjob(x_ln_bf, qkvT, b_qkv, nullptr, nullptr, nullptr, q2b, k2b, v2b,
                       2048, 512, 8, 1536, 1536, 0);
        P.j[1] = mkjob(gene_bf, wa1gT, nullptr, nullptr, nullptr, gep, gepb, nullptr,
                       nullptr, 2048, 64, 1, 512, 512, 192);
        gemm_bf16_kernel<<<256, 256, 0, stream>>>(P);
    }
    // 4. BATCH{qp, kg(fp32 out), edge}: 512+512+256 = 1280 blocks
    {
        GJobs P;
        P.nj = 3;
        P.j[0] = mkjob(q2b, wa1qT, ba1, nullptr, nullptr, nullptr, qpb, nullptr, nullptr,
                       16384, 64, 1, 512, 512, 0);
        P.j[1] = mkjob(k2b, wa1kT, nullptr, nullptr, gep, kgf, nullptr, nullptr, nullptr,
                       16384, 64, 1, 512, 512, 512);
        P.j[2] = mkjob(u_bf, we2T, be2, nullptr, nullptr, nullptr, edgeb, nullptr,
                       nullptr, 32768, 128, 2, 128, 128, 1024);
        gemm_bf16_kernel<<<1280, 256, 0, stream>>>(P);
    }
    // 5. fused logits + softmax + aggregation -> scec bf16
    logits_fused_kernel<<<2048, 256, 0, stream>>>(qpb, kgf, gepb, edgeb, wesT, nbr,
                                                  wa2, ba2, v2b, scec_bf);
    // 6. ctx = mlp2(scec, wo1, wo2); tok1 = token_embs + ctx
    Gsk2(scec_bf, wo1T, 2048, 640, 512);
    combine2ln_kernel<<<2048, 256, 0, stream>>>(pk4, bo1, buf1_bf);
    Gsk2(buf1_bf, wo2T, 2048, 512, 512);
    combine2_kernel<<<4096, 256, 0, stream>>>(pk4, bo2, token_embs, tok1, tok1_bf);
    // 7. tok2 = tok1 + mlp2(tok1, wm1, wm2) -> d_out tok section
    G1(tok1_bf, wm1T, bm1, nullptr, nullptr, buf2, nullptr, 2048, 512, 2048, 2048);
    act_ln_kernel<<<2048, 256, 0, stream>>>(nullptr, buf2_bf, buf2, 2048, 1);
    {
        // wm2 split-K=4 as one batched launch (4x64 = 256 blocks), fp32 partials
        GJobs P;
        P.nj = 4;
#pragma unroll
        for (int s = 0; s < 4; ++s)
            P.j[s] = mkjob(buf2_bf + s * 512, wm2T + s * 512, nullptr, nullptr, nullptr,
                           pk4 + (size_t)s * 1048576, nullptr, nullptr, nullptr,
                           2048, 2048, 8, 512, 512, s * 64);
        gemm_bf16_kernel<<<256, 256, 0, stream>>>(P);
        wm2_combine<<<4096, 256, 0, stream>>>(pk4, bm2, tok1, tok_out, tokout_bf);
    }
    // 8. gene_out = mlp2(tok2, wg1, wg2)
    Gsk2(tokout_bf, wg1T, 2048, 512, 512);
    combine2ln_kernel<<<2048, 256, 0, stream>>>(pk4, bg1, buf1_bf);
    {
        // wg2 split-K=4: 4x16 = 64 blocks, partials [2048,50] each
        GJobs P;
        P.nj = 4;
#pragma unroll
        for (int s = 0; s < 4; ++s)
            P.j[s] = mkjob(buf1_bf + s * 128, wg2T + s * 128, nullptr, nullptr, nullptr,
                           pk4 + (size_t)s * 102400, nullptr, nullptr, nullptr,
                           2048, 512, 2, 128, 50, s * 16);
        gemm_bf16_kernel<<<64, 256, 0, stream>>>(P);
        wg2_combine<<<400, 256, 0, stream>>>(pk4, bg2, gene_out);
    }
}